// Round 12
// baseline (439.525 us; speedup 1.0000x reference)
//
#include <hip/hip_runtime.h>
#include <hip/hip_cooperative_groups.h>

namespace cg = cooperative_groups;

#define T_LEN     32768
#define KTAG      5
#define START_TAG 3
#define STOP_TAG  4
#define NEGV      (-10000.0f)
#define CHUNK     64
#define NCHUNK    512      // T_LEN / CHUNK
// scan segmentation inside block 0 (4 waves)
#define NSEG_S    4
#define SEGLEN_S  128      // NCHUNK / NSEG_S
// backtrack segmentation (block 0, lanes<16)
#define NSEG_B    16
#define SEGLEN_B  32       // NCHUNK / NSEG_B

// ---------------------------------------------------------------------------
// K1: emissions[t][k] = dot(feats[t], W[k]) + b[k].  One wave per row t.
// (unchanged from the passing round-9 kernel)
// ---------------------------------------------------------------------------
__global__ __launch_bounds__(256) void k_emis(const float* __restrict__ feats,
                                              const float* __restrict__ W,
                                              const float* __restrict__ b,
                                              float* __restrict__ emis) {
    int tid  = blockIdx.x * 256 + threadIdx.x;
    int row  = tid >> 6;
    int lane = tid & 63;
    if (row >= T_LEN) return;

    const float4* f4 = (const float4*)feats + row * 256;
    const float4* Wq = (const float4*)W;

    float a0 = 0.f, a1 = 0.f, a2 = 0.f, a3 = 0.f, a4 = 0.f;
#pragma unroll
    for (int j = 0; j < 4; ++j) {
        float4 f  = f4[j * 64 + lane];
        float4 w0 = Wq[0 * 256 + j * 64 + lane];
        float4 w1 = Wq[1 * 256 + j * 64 + lane];
        float4 w2 = Wq[2 * 256 + j * 64 + lane];
        float4 w3 = Wq[3 * 256 + j * 64 + lane];
        float4 w4 = Wq[4 * 256 + j * 64 + lane];
        a0 += f.x * w0.x + f.y * w0.y + f.z * w0.z + f.w * w0.w;
        a1 += f.x * w1.x + f.y * w1.y + f.z * w1.z + f.w * w1.w;
        a2 += f.x * w2.x + f.y * w2.y + f.z * w2.z + f.w * w2.w;
        a3 += f.x * w3.x + f.y * w3.y + f.z * w3.z + f.w * w3.w;
        a4 += f.x * w4.x + f.y * w4.y + f.z * w4.z + f.w * w4.w;
    }
#pragma unroll
    for (int s = 1; s < 64; s <<= 1) {
        a0 += __shfl_xor(a0, s, 64);
        a1 += __shfl_xor(a1, s, 64);
        a2 += __shfl_xor(a2, s, 64);
        a3 += __shfl_xor(a3, s, 64);
        a4 += __shfl_xor(a4, s, 64);
    }
    if (lane < KTAG) {
        float r = (lane == 0) ? a0 : (lane == 1) ? a1 : (lane == 2) ? a2
                                   : (lane == 3) ? a3 : a4;
        emis[row * KTAG + lane] = r + b[lane];
    }
}

// ---------------------------------------------------------------------------
// K2 (fused, cooperative): chunkmat -> scan -> replay -> back -> path.
// 512 blocks x 256 threads; block b owns chunk b; emissions + backpointers
// for the chunk live in LDS.  grid.sync() between cross-block phases.
// ---------------------------------------------------------------------------
__global__ __launch_bounds__(256) void k_viterbi(const float* __restrict__ emis,
                                                 const float* __restrict__ trans,
                                                 float* __restrict__ P_g,
                                                 float* __restrict__ vc_g,
                                                 unsigned short* __restrict__ F16,
                                                 unsigned int* __restrict__ Ec,
                                                 unsigned int* __restrict__ best_g,
                                                 float* __restrict__ out) {
    cg::grid_group grid = cg::this_grid();

    __shared__ float          Pl[NCHUNK * 25];     // 51200 B (used by block 0)
    __shared__ float          Sl[NSEG_S * 25];
    __shared__ float          vsup[NSEG_S * 5];
    __shared__ float          emis_lds[CHUNK * KTAG];
    __shared__ unsigned short bp_lds[CHUNK];
    __shared__ unsigned int   sm[NSEG_B];
    __shared__ unsigned int   esup[NSEG_B];

    int b    = blockIdx.x;
    int tid  = threadIdx.x;
    int w    = tid >> 6;
    int lane = tid & 63;

    // stage this chunk's emissions into LDS (coalesced)
    for (int i = tid; i < CHUNK * KTAG; i += 256)
        emis_lds[i] = emis[b * CHUNK * KTAG + i];
    __syncthreads();

    // ---- Phase C: per-chunk max-plus product (wave 0, lanes 0..24)
    if (w == 0 && lane < 25) {
        int n = lane / 5, p = lane % 5;
        float tr0 = trans[n * 5 + 0], tr1 = trans[n * 5 + 1], tr2 = trans[n * 5 + 2];
        float tr3 = trans[n * 5 + 3], tr4 = trans[n * 5 + 4];
        float A = trans[n * 5 + p] + emis_lds[0 * 5 + n];
        for (int j = 1; j < CHUNK; ++j) {
            float e  = emis_lds[j * 5 + n];
            float q0 = __shfl(A, 0 * 5 + p, 64);
            float q1 = __shfl(A, 1 * 5 + p, 64);
            float q2 = __shfl(A, 2 * 5 + p, 64);
            float q3 = __shfl(A, 3 * 5 + p, 64);
            float q4 = __shfl(A, 4 * 5 + p, 64);
            float m  = tr0 + q0;
            m = fmaxf(m, tr1 + q1);
            m = fmaxf(m, tr2 + q2);
            m = fmaxf(m, tr3 + q3);
            m = fmaxf(m, tr4 + q4);
            A = m + e;
        }
        P_g[b * 25 + lane] = A;
    }
    grid.sync();

    // ---- Phase S: hierarchical scan over 512 chunk matrices (block 0 only)
    if (b == 0) {
        for (int i = tid; i < NCHUNK * 25; i += 256) Pl[i] = P_g[i];
        __syncthreads();
        // S1: wave w composes its 128 chunk matrices
        if (lane < 25) {
            int n = lane / 5, p = lane % 5;
            float A = Pl[(w * SEGLEN_S) * 25 + lane];
            for (int j = 1; j < SEGLEN_S; ++j) {
                const float* Pn = &Pl[(w * SEGLEN_S + j) * 25 + n * 5];
                float q0 = __shfl(A, 0 * 5 + p, 64);
                float q1 = __shfl(A, 1 * 5 + p, 64);
                float q2 = __shfl(A, 2 * 5 + p, 64);
                float q3 = __shfl(A, 3 * 5 + p, 64);
                float q4 = __shfl(A, 4 * 5 + p, 64);
                float m  = Pn[0] + q0;
                m = fmaxf(m, Pn[1] + q1);
                m = fmaxf(m, Pn[2] + q2);
                m = fmaxf(m, Pn[3] + q3);
                m = fmaxf(m, Pn[4] + q4);
                A = m;
            }
            Sl[w * 25 + lane] = A;
        }
        __syncthreads();
        // S2: wave 0 lanes 0..4 propagate init through the 4 supermatrices
        if (tid < 5) {
            float v = (tid == START_TAG) ? 0.0f : NEGV;
            for (int s = 0; s < NSEG_S; ++s) {
                vsup[s * 5 + tid] = v;
                float q0 = __shfl(v, 0, 64);
                float q1 = __shfl(v, 1, 64);
                float q2 = __shfl(v, 2, 64);
                float q3 = __shfl(v, 3, 64);
                float q4 = __shfl(v, 4, 64);
                const float* S = &Sl[s * 25 + tid * 5];
                float m = S[0] + q0;
                m = fmaxf(m, S[1] + q1);
                m = fmaxf(m, S[2] + q2);
                m = fmaxf(m, S[3] + q3);
                m = fmaxf(m, S[4] + q4);
                v = m;
            }
            float term = v + trans[STOP_TAG * 5 + tid];
            float c0 = __shfl(term, 0, 64);
            float c1 = __shfl(term, 1, 64);
            float c2 = __shfl(term, 2, 64);
            float c3 = __shfl(term, 3, 64);
            float c4 = __shfl(term, 4, 64);
            float bv = c0; int bi = 0;
            if (c1 > bv) { bv = c1; bi = 1; }
            if (c2 > bv) { bv = c2; bi = 2; }
            if (c3 > bv) { bv = c3; bi = 3; }
            if (c4 > bv) { bv = c4; bi = 4; }
            if (tid == 0) { out[0] = bv; best_g[0] = (unsigned int)bi; }
        }
        __syncthreads();
        // S3: wave w propagates v through its segment, storing chunk-start vecs
        if (lane < 5) {
            float v = vsup[w * 5 + lane];
            for (int j = 0; j < SEGLEN_S; ++j) {
                int c = w * SEGLEN_S + j;
                vc_g[c * 5 + lane] = v;
                const float* Pn = &Pl[c * 25 + lane * 5];
                float q0 = __shfl(v, 0, 64);
                float q1 = __shfl(v, 1, 64);
                float q2 = __shfl(v, 2, 64);
                float q3 = __shfl(v, 3, 64);
                float q4 = __shfl(v, 4, 64);
                float m  = Pn[0] + q0;
                m = fmaxf(m, Pn[1] + q1);
                m = fmaxf(m, Pn[2] + q2);
                m = fmaxf(m, Pn[3] + q3);
                m = fmaxf(m, Pn[4] + q4);
                v = m;
            }
        }
    }
    grid.sync();

    // ---- Phase R: replay chunk from exact start vector (wave 0, lanes 0..4)
    if (w == 0 && lane < 5) {
        int n = lane;
        float tr0 = trans[n * 5 + 0], tr1 = trans[n * 5 + 1], tr2 = trans[n * 5 + 2];
        float tr3 = trans[n * 5 + 3], tr4 = trans[n * 5 + 4];
        float v = vc_g[b * 5 + n];
        int G = n;
        for (int j = 0; j < CHUNK; ++j) {
            float e  = emis_lds[j * 5 + n];
            float q0 = __shfl(v, 0, 64);
            float q1 = __shfl(v, 1, 64);
            float q2 = __shfl(v, 2, 64);
            float q3 = __shfl(v, 3, 64);
            float q4 = __shfl(v, 4, 64);
            float c0 = tr0 + q0, c1 = tr1 + q1, c2 = tr2 + q2, c3 = tr3 + q3, c4 = tr4 + q4;
            float bv = c0; int bp = 0;
            if (c1 > bv) { bv = c1; bp = 1; }
            if (c2 > bv) { bv = c2; bp = 2; }
            if (c3 > bv) { bv = c3; bp = 3; }
            if (c4 > bv) { bv = c4; bp = 4; }
            v = bv + e;
            G = __shfl(G, bp, 64);
            int b0 = __shfl(bp, 0, 64);
            int b1 = __shfl(bp, 1, 64);
            int b2 = __shfl(bp, 2, 64);
            int b3 = __shfl(bp, 3, 64);
            int b4 = __shfl(bp, 4, 64);
            if (lane == 0)
                bp_lds[j] = (unsigned short)(b0 | (b1 << 3) | (b2 << 6) | (b3 << 9) | (b4 << 12));
        }
        int g0 = __shfl(G, 0, 64);
        int g1 = __shfl(G, 1, 64);
        int g2 = __shfl(G, 2, 64);
        int g3 = __shfl(G, 3, 64);
        int g4 = __shfl(G, 4, 64);
        if (lane == 0)
            F16[b] = (unsigned short)(g0 | (g1 << 3) | (g2 << 6) | (g3 << 9) | (g4 << 12));
    }
    grid.sync();

    // ---- Phase B: hierarchical suffix maps -> Ec[c] (block 0 only)
    if (b == 0) {
        if (tid < NSEG_B) {
            unsigned int G = 0u | (1u << 3) | (2u << 6) | (3u << 9) | (4u << 12);
            int base = tid * SEGLEN_B;
            for (int j = SEGLEN_B - 1; j >= 0; --j) {
                unsigned int f  = F16[base + j];
                unsigned int Gn = 0;
#pragma unroll
                for (int x = 0; x < 5; ++x) {
                    unsigned int gx = (G >> (3 * x)) & 7u;
                    unsigned int ex = (f >> (3 * gx)) & 7u;
                    Gn |= ex << (3 * x);
                }
                G = Gn;
            }
            sm[tid] = G;
        }
        __syncthreads();
        if (tid == 0) {
            unsigned int E = best_g[0];
            for (int s = NSEG_B - 1; s >= 0; --s) {
                esup[s] = E;
                E = (sm[s] >> (3 * E)) & 7u;
            }
        }
        __syncthreads();
        if (tid < NSEG_B) {
            unsigned int E = esup[tid];
            int base = tid * SEGLEN_B;
            for (int j = SEGLEN_B - 1; j >= 0; --j) {
                Ec[base + j] = E;
                unsigned int f = F16[base + j];
                E = (f >> (3 * E)) & 7u;
            }
        }
    }
    grid.sync();

    // ---- Phase P: emit path for this chunk (wave 0, backpointers in LDS)
    if (w == 0) {
        int pk = (int)bp_lds[lane];
        unsigned int carry  = Ec[b];
        unsigned int mypath = 0;
#pragma unroll
        for (int j = CHUNK - 1; j >= 0; --j) {
            int pkj = __shfl(pk, j, 64);
            if (lane == j) mypath = carry;
            carry = ((unsigned int)pkj >> (3 * carry)) & 7u;
        }
        out[1 + b * CHUNK + lane] = (float)mypath;
    }
}

// ---------------------------------------------------------------------------
extern "C" void kernel_launch(void* const* d_in, const int* in_sizes, int n_in,
                              void* d_out, int out_size, void* d_ws, size_t ws_size,
                              hipStream_t stream) {
    const float* feats = (const float*)d_in[0];   // [1, 32768, 1024]
    const float* W     = (const float*)d_in[1];   // [5, 1024]
    const float* bias  = (const float*)d_in[2];   // [5]
    const float* trans = (const float*)d_in[3];   // [5, 5]
    float* out = (float*)d_out;                   // [1 + 32768]

    char* ws = (char*)d_ws;
    float*          emis = (float*)(ws + 0);              // 32768*5*4
    float*          P    = (float*)(ws + 655360);         // 512*25*4
    float*          vc   = (float*)(ws + 706560);         // 512*5*4
    unsigned short* F16  = (unsigned short*)(ws + 782336);// 512*2
    unsigned int*   Ec   = (unsigned int*)(ws + 783360);  // 512*4
    unsigned int*   best = (unsigned int*)(ws + 785408);  // 4

    hipLaunchKernelGGL(k_emis, dim3(8192), dim3(256), 0, stream, feats, W, bias, emis);

    void* args[] = { (void*)&emis, (void*)&trans, (void*)&P, (void*)&vc,
                     (void*)&F16, (void*)&Ec, (void*)&best, (void*)&out };
    hipLaunchCooperativeKernel((const void*)k_viterbi, dim3(NCHUNK), dim3(256),
                               args, 0, stream);
}

// Round 13
// 256.732 us; speedup vs baseline: 1.7120x; 1.7120x over previous
//
#include <hip/hip_runtime.h>

#define T_LEN     32768
#define KTAG      5
#define START_TAG 3
#define STOP_TAG  4
#define NEGV      (-10000.0f)
#define CHUNK     64
#define NCHUNK    512      // T_LEN / CHUNK
#define NSEG      16
#define SEGLEN    32       // NCHUNK / NSEG

// ---------------------------------------------------------------------------
// K1: emissions[t][k] = dot(feats[t], W[k]) + b[k].  One wave per row t.
// (verbatim from the passing round-9 kernel)
// ---------------------------------------------------------------------------
__global__ __launch_bounds__(256) void k_emis(const float* __restrict__ feats,
                                              const float* __restrict__ W,
                                              const float* __restrict__ b,
                                              float* __restrict__ emis) {
    int tid  = blockIdx.x * 256 + threadIdx.x;
    int row  = tid >> 6;
    int lane = tid & 63;
    if (row >= T_LEN) return;

    const float4* f4 = (const float4*)feats + row * 256;
    const float4* Wq = (const float4*)W;

    float a0 = 0.f, a1 = 0.f, a2 = 0.f, a3 = 0.f, a4 = 0.f;
#pragma unroll
    for (int j = 0; j < 4; ++j) {
        float4 f  = f4[j * 64 + lane];
        float4 w0 = Wq[0 * 256 + j * 64 + lane];
        float4 w1 = Wq[1 * 256 + j * 64 + lane];
        float4 w2 = Wq[2 * 256 + j * 64 + lane];
        float4 w3 = Wq[3 * 256 + j * 64 + lane];
        float4 w4 = Wq[4 * 256 + j * 64 + lane];
        a0 += f.x * w0.x + f.y * w0.y + f.z * w0.z + f.w * w0.w;
        a1 += f.x * w1.x + f.y * w1.y + f.z * w1.z + f.w * w1.w;
        a2 += f.x * w2.x + f.y * w2.y + f.z * w2.z + f.w * w2.w;
        a3 += f.x * w3.x + f.y * w3.y + f.z * w3.z + f.w * w3.w;
        a4 += f.x * w4.x + f.y * w4.y + f.z * w4.z + f.w * w4.w;
    }
#pragma unroll
    for (int s = 1; s < 64; s <<= 1) {
        a0 += __shfl_xor(a0, s, 64);
        a1 += __shfl_xor(a1, s, 64);
        a2 += __shfl_xor(a2, s, 64);
        a3 += __shfl_xor(a3, s, 64);
        a4 += __shfl_xor(a4, s, 64);
    }
    if (lane < KTAG) {
        float r = (lane == 0) ? a0 : (lane == 1) ? a1 : (lane == 2) ? a2
                                   : (lane == 3) ? a3 : a4;
        emis[row * KTAG + lane] = r + b[lane];
    }
}

// ---------------------------------------------------------------------------
// K2: per-chunk max-plus matrix product (verbatim round-9).
// ---------------------------------------------------------------------------
__global__ __launch_bounds__(64) void k_chunkmat(const float* __restrict__ emis,
                                                 const float* __restrict__ trans,
                                                 float* __restrict__ P) {
    int c    = blockIdx.x;
    int lane = threadIdx.x;
    if (lane >= 25) return;
    int n = lane / 5, p = lane % 5;

    float tr0 = trans[n * 5 + 0], tr1 = trans[n * 5 + 1], tr2 = trans[n * 5 + 2];
    float tr3 = trans[n * 5 + 3], tr4 = trans[n * 5 + 4];

    int t0 = c * CHUNK;
    float A = trans[n * 5 + p] + emis[t0 * KTAG + n];
    for (int j = 1; j < CHUNK; ++j) {
        float e  = emis[(t0 + j) * KTAG + n];
        float q0 = __shfl(A, 0 * 5 + p, 64);
        float q1 = __shfl(A, 1 * 5 + p, 64);
        float q2 = __shfl(A, 2 * 5 + p, 64);
        float q3 = __shfl(A, 3 * 5 + p, 64);
        float q4 = __shfl(A, 4 * 5 + p, 64);
        float m  = tr0 + q0;
        m = fmaxf(m, tr1 + q1);
        m = fmaxf(m, tr2 + q2);
        m = fmaxf(m, tr3 + q3);
        m = fmaxf(m, tr4 + q4);
        A = m + e;
    }
    P[c * 25 + lane] = A;
}

// ---------------------------------------------------------------------------
// K3: single-block hierarchical scan (verbatim round-9, 1024 threads).
// ---------------------------------------------------------------------------
__global__ __launch_bounds__(1024) void k_scan(const float* __restrict__ P,
                                               const float* __restrict__ trans,
                                               float* __restrict__ vc,
                                               float* __restrict__ score_out,
                                               unsigned int* __restrict__ best_out) {
    __shared__ float Pl[NCHUNK * 25];
    __shared__ float Sl[NSEG * 25];
    __shared__ float vsup[NSEG * 5];

    int tid = threadIdx.x;
    for (int i = tid; i < NCHUNK * 25; i += 1024) Pl[i] = P[i];
    __syncthreads();

    int w = tid >> 6, lane = tid & 63;

    if (lane < 25) {
        int n = lane / 5, p = lane % 5;
        float A = Pl[(w * SEGLEN) * 25 + lane];
        for (int j = 1; j < SEGLEN; ++j) {
            const float* Pn = &Pl[(w * SEGLEN + j) * 25 + n * 5];
            float q0 = __shfl(A, 0 * 5 + p, 64);
            float q1 = __shfl(A, 1 * 5 + p, 64);
            float q2 = __shfl(A, 2 * 5 + p, 64);
            float q3 = __shfl(A, 3 * 5 + p, 64);
            float q4 = __shfl(A, 4 * 5 + p, 64);
            float m  = Pn[0] + q0;
            m = fmaxf(m, Pn[1] + q1);
            m = fmaxf(m, Pn[2] + q2);
            m = fmaxf(m, Pn[3] + q3);
            m = fmaxf(m, Pn[4] + q4);
            A = m;
        }
        Sl[w * 25 + lane] = A;
    }
    __syncthreads();

    if (tid < 5) {
        float v = (tid == START_TAG) ? 0.0f : NEGV;
        for (int s = 0; s < NSEG; ++s) {
            vsup[s * 5 + tid] = v;
            float q0 = __shfl(v, 0, 64);
            float q1 = __shfl(v, 1, 64);
            float q2 = __shfl(v, 2, 64);
            float q3 = __shfl(v, 3, 64);
            float q4 = __shfl(v, 4, 64);
            const float* S = &Sl[s * 25 + tid * 5];
            float m = S[0] + q0;
            m = fmaxf(m, S[1] + q1);
            m = fmaxf(m, S[2] + q2);
            m = fmaxf(m, S[3] + q3);
            m = fmaxf(m, S[4] + q4);
            v = m;
        }
        float term = v + trans[STOP_TAG * 5 + tid];
        float c0 = __shfl(term, 0, 64);
        float c1 = __shfl(term, 1, 64);
        float c2 = __shfl(term, 2, 64);
        float c3 = __shfl(term, 3, 64);
        float c4 = __shfl(term, 4, 64);
        float bv = c0; int bi = 0;
        if (c1 > bv) { bv = c1; bi = 1; }
        if (c2 > bv) { bv = c2; bi = 2; }
        if (c3 > bv) { bv = c3; bi = 3; }
        if (c4 > bv) { bv = c4; bi = 4; }
        if (tid == 0) { score_out[0] = bv; best_out[0] = (unsigned int)bi; }
    }
    __syncthreads();

    if (lane < 5) {
        float v = vsup[w * 5 + lane];
        for (int j = 0; j < SEGLEN; ++j) {
            int c = w * SEGLEN + j;
            vc[c * 5 + lane] = v;
            const float* Pn = &Pl[c * 25 + lane * 5];
            float q0 = __shfl(v, 0, 64);
            float q1 = __shfl(v, 1, 64);
            float q2 = __shfl(v, 2, 64);
            float q3 = __shfl(v, 3, 64);
            float q4 = __shfl(v, 4, 64);
            float m  = Pn[0] + q0;
            m = fmaxf(m, Pn[1] + q1);
            m = fmaxf(m, Pn[2] + q2);
            m = fmaxf(m, Pn[3] + q3);
            m = fmaxf(m, Pn[4] + q4);
            v = m;
        }
    }
}

// ---------------------------------------------------------------------------
// K4: per-chunk replay (verbatim round-9): packed backpointers + chunk map.
// ---------------------------------------------------------------------------
__global__ __launch_bounds__(64) void k_replay(const float* __restrict__ emis,
                                               const float* __restrict__ trans,
                                               const float* __restrict__ vc,
                                               unsigned short* __restrict__ bp16,
                                               unsigned short* __restrict__ F16) {
    int c    = blockIdx.x;
    int lane = threadIdx.x;
    if (lane >= 5) return;
    int n = lane;

    float tr0 = trans[n * 5 + 0], tr1 = trans[n * 5 + 1], tr2 = trans[n * 5 + 2];
    float tr3 = trans[n * 5 + 3], tr4 = trans[n * 5 + 4];

    float v = vc[c * 5 + n];
    int G = n;
    int t0 = c * CHUNK;
    for (int j = 0; j < CHUNK; ++j) {
        int t = t0 + j;
        float e  = emis[t * KTAG + n];
        float q0 = __shfl(v, 0, 64);
        float q1 = __shfl(v, 1, 64);
        float q2 = __shfl(v, 2, 64);
        float q3 = __shfl(v, 3, 64);
        float q4 = __shfl(v, 4, 64);
        float c0 = tr0 + q0, c1 = tr1 + q1, c2 = tr2 + q2, c3 = tr3 + q3, c4 = tr4 + q4;
        float bv = c0; int bp = 0;
        if (c1 > bv) { bv = c1; bp = 1; }
        if (c2 > bv) { bv = c2; bp = 2; }
        if (c3 > bv) { bv = c3; bp = 3; }
        if (c4 > bv) { bv = c4; bp = 4; }
        v = bv + e;
        G = __shfl(G, bp, 64);
        int b0 = __shfl(bp, 0, 64);
        int b1 = __shfl(bp, 1, 64);
        int b2 = __shfl(bp, 2, 64);
        int b3 = __shfl(bp, 3, 64);
        int b4 = __shfl(bp, 4, 64);
        if (lane == 0)
            bp16[t] = (unsigned short)(b0 | (b1 << 3) | (b2 << 6) | (b3 << 9) | (b4 << 12));
    }
    int g0 = __shfl(G, 0, 64);
    int g1 = __shfl(G, 1, 64);
    int g2 = __shfl(G, 2, 64);
    int g3 = __shfl(G, 3, 64);
    int g4 = __shfl(G, 4, 64);
    if (lane == 0)
        F16[c] = (unsigned short)(g0 | (g1 << 3) | (g2 << 6) | (g3 << 9) | (g4 << 12));
}

// ---------------------------------------------------------------------------
// K5 (merged back+path): each block locally recomputes the 16-segment suffix
// maps (k_back's exact logic, redundant per block — deterministic ALU), derives
// its own chunk's entry tag, then does the 64-step in-register chase.
// ---------------------------------------------------------------------------
__global__ __launch_bounds__(64) void k_pathback(const unsigned short* __restrict__ bp16,
                                                 const unsigned short* __restrict__ F16,
                                                 const unsigned int* __restrict__ best_in,
                                                 float* __restrict__ out) {
    __shared__ unsigned int sm[NSEG];
    __shared__ unsigned int esup[NSEG];
    __shared__ unsigned int Ec_l;

    int c    = blockIdx.x;
    int lane = threadIdx.x;

    // segment map composition (identical to k_back's first phase)
    if (lane < NSEG) {
        unsigned int G = 0u | (1u << 3) | (2u << 6) | (3u << 9) | (4u << 12);
        int base = lane * SEGLEN;
        for (int j = SEGLEN - 1; j >= 0; --j) {
            unsigned int f  = F16[base + j];
            unsigned int Gn = 0;
#pragma unroll
            for (int x = 0; x < 5; ++x) {
                unsigned int gx = (G >> (3 * x)) & 7u;
                unsigned int ex = (f >> (3 * gx)) & 7u;
                Gn |= ex << (3 * x);
            }
            G = Gn;
        }
        sm[lane] = G;
    }
    __syncthreads();
    // segment-entry walk (identical to k_back's second phase)
    if (lane == 0) {
        unsigned int E = best_in[0];
        for (int s = NSEG - 1; s >= 0; --s) {
            esup[s] = E;
            E = (sm[s] >> (3 * E)) & 7u;
        }
        // within-segment walk down to THIS chunk (k_back third phase, scoped)
        int s    = c / SEGLEN;
        int base = s * SEGLEN;
        unsigned int Ew = esup[s];
        for (int j = SEGLEN - 1; j > c - base; --j)
            Ew = (F16[base + j] >> (3 * Ew)) & 7u;
        Ec_l = Ew;
    }
    __syncthreads();

    // 64-step chase (identical to round-9 k_path)
    int pk = (int)bp16[c * 64 + lane];
    unsigned int carry  = Ec_l;
    unsigned int mypath = 0;
#pragma unroll
    for (int j = 63; j >= 0; --j) {
        int pkj = __shfl(pk, j, 64);
        if (lane == j) mypath = carry;
        carry = ((unsigned int)pkj >> (3 * carry)) & 7u;
    }
    out[1 + c * 64 + lane] = (float)mypath;
}

// ---------------------------------------------------------------------------
extern "C" void kernel_launch(void* const* d_in, const int* in_sizes, int n_in,
                              void* d_out, int out_size, void* d_ws, size_t ws_size,
                              hipStream_t stream) {
    const float* feats = (const float*)d_in[0];   // [1, 32768, 1024]
    const float* W     = (const float*)d_in[1];   // [5, 1024]
    const float* bias  = (const float*)d_in[2];   // [5]
    const float* trans = (const float*)d_in[3];   // [5, 5]
    float* out = (float*)d_out;                   // [1 + 32768]

    char* ws = (char*)d_ws;
    float*          emis = (float*)(ws + 0);              // 32768*5*4
    float*          P    = (float*)(ws + 655360);         // 512*25*4
    float*          vc   = (float*)(ws + 706560);         // 512*5*4
    unsigned short* bp16 = (unsigned short*)(ws + 716800);// 32768*2
    unsigned short* F16  = (unsigned short*)(ws + 782336);// 512*2
    unsigned int*   best = (unsigned int*)(ws + 785408);  // 4

    hipLaunchKernelGGL(k_emis,     dim3(8192), dim3(256),  0, stream, feats, W, bias, emis);
    hipLaunchKernelGGL(k_chunkmat, dim3(NCHUNK), dim3(64), 0, stream, emis, trans, P);
    hipLaunchKernelGGL(k_scan,     dim3(1), dim3(1024),    0, stream, P, trans, vc, out, best);
    hipLaunchKernelGGL(k_replay,   dim3(NCHUNK), dim3(64), 0, stream, emis, trans, vc, bp16, F16);
    hipLaunchKernelGGL(k_pathback, dim3(NCHUNK), dim3(64), 0, stream, bp16, F16, best, out);
}